// Round 2
// baseline (657.028 us; speedup 1.0000x reference)
//
#include <hip/hip_runtime.h>
#include <hip/hip_bf16.h>

#define BM 64
#define BN 32
#define BK 16

// ---- dual-dtype element access (flag: 0 = bf16, 1 = f32) ----
static __device__ __forceinline__ float ldv(const void* p, size_t i, int f32m) {
    if (f32m) return ((const float*)p)[i];
    return __bfloat162float(((const __hip_bfloat16*)p)[i]);
}
static __device__ __forceinline__ void stv(void* p, size_t i, float v, int f32m) {
    if (f32m) ((float*)p)[i] = v;
    else ((__hip_bfloat16*)p)[i] = __float2bfloat16(v);
}

// Robust scalar decode: handles int32, float32, or bf16-in-low-16 encodings.
static __device__ __forceinline__ float decode_scalar(const void* p) {
    unsigned u = *(const unsigned*)p;
    unsigned e32 = (u >> 23) & 0xff;
    if (e32 >= 97 && e32 <= 160) return __uint_as_float(u);          // plausible f32
    unsigned lo = u & 0xffffu;
    unsigned e16 = (lo >> 7) & 0xff;
    if ((u >> 16) == 0 && e16 >= 97 && e16 <= 160)
        return __uint_as_float(lo << 16);                             // plausible bf16
    return (float)(int)u;                                             // int32
}

__device__ __forceinline__ float wave_sum(float v) {
    #pragma unroll
    for (int o = 32; o > 0; o >>= 1) v += __shfl_down(v, o, 64);
    return v;
}
__device__ __forceinline__ float wave_max(float v) {
    #pragma unroll
    for (int o = 32; o > 0; o >>= 1) v = fmaxf(v, __shfl_down(v, o, 64));
    return v;
}

// K0: decide whether float inputs are bf16 (flag=0) or f32 (flag=1).
__global__ void sniff_dtype(const void* __restrict__ feat, int nSample, int* __restrict__ flag) {
    __shared__ int cnt;
    if (threadIdx.x == 0) cnt = 0;
    __syncthreads();
    const __hip_bfloat16* p = (const __hip_bfloat16*)feat;
    int local = 0;
    for (int i = threadIdx.x; i < nSample; i += 256) {
        float v = __bfloat162float(p[i]);
        if (!(fabsf(v) < 1e10f)) local++;   // catches huge, Inf, NaN
    }
    atomicAdd(&cnt, local);
    __syncthreads();
    if (threadIdx.x == 0) flag[0] = (cnt > 16) ? 1 : 0;
}

// K1: segment sums of x and x^2 per class, plus counts.
__global__ void accum_stats(const void* __restrict__ feat,
                            const int* __restrict__ labels,
                            float* __restrict__ sums, float* __restrict__ sqs,
                            float* __restrict__ counts, const int* __restrict__ flag,
                            int Nn, int A) {
    int f32m = flag[0];
    int idx = blockIdx.x * 256 + threadIdx.x;
    if (idx >= Nn * A) return;
    int n = idx / A;
    int a = idx - n * A;
    int l = labels[n];
    float x = ldv(feat, idx, f32m);
    atomicAdd(&sums[(size_t)l * A + a], x);
    atomicAdd(&sqs[(size_t)l * A + a], x * x);
    if (a == 0) atomicAdd(&counts[l], 1.0f);
}

// K2: finalize stats. Writes new_ave/new_cov/new_amount into d_out at given
// element offsets, and an f32 ncov copy into ws (aliased onto sqs).
__global__ void finalize_stats(const float* __restrict__ sums, float* __restrict__ sqs_ncov,
                               const float* __restrict__ counts,
                               const void* __restrict__ ave,
                               const void* __restrict__ cov,
                               const void* __restrict__ amount,
                               void* __restrict__ out,
                               size_t off_ave, size_t off_cov, size_t off_amt,
                               const int* __restrict__ flag,
                               int C, int A) {
    int f32m = flag[0];
    int idx = blockIdx.x * 256 + threadIdx.x;
    if (idx >= C * A) return;
    int c = idx / A;
    int a = idx - c * A;
    float cnt = counts[c];
    float denom = cnt > 0.f ? cnt : 1.f;
    float mean = sums[idx] / denom;
    float var = (sqs_ncov[idx] - cnt * mean * mean) / denom;
    var = fmaxf(var, 0.f);
    float amt = ldv(amount, c, f32m);
    float tot = cnt + amt;
    float w = tot > 0.f ? (cnt / tot) : 0.f;   // nan_to_num(0/0) -> 0
    float av = ldv(ave, idx, f32m);
    float cv = ldv(cov, idx, f32m);
    float d = av - mean;
    float ncv = cv * (1.f - w) + var * w + w * (1.f - w) * d * d;
    float nav = av * (1.f - w) + mean * w;
    stv(out, off_cov + idx, ncv, f32m);
    stv(out, off_ave + idx, nav, f32m);
    sqs_ncov[idx] = ncv;                      // read-then-write same element: safe
    if (a == 0) stv(out, off_amt + c, amt + cnt, f32m);
}

// K3: t3[n] = sum_a W[l,a]^2 * ncov[l,a]
__global__ void compute_t3(const void* __restrict__ W,
                           const float* __restrict__ ncov,
                           const int* __restrict__ labels,
                           float* __restrict__ t3, const int* __restrict__ flag, int A) {
    __shared__ float sb[4];
    int f32m = flag[0];
    int n = blockIdx.x;
    int l = labels[n];
    float s = 0.f;
    for (int a = threadIdx.x; a < A; a += 256) {
        float w = ldv(W, (size_t)l * A + a, f32m);
        float cv = ncov[(size_t)l * A + a];
        s += w * w * cv;
    }
    s = wave_sum(s);
    int lane = threadIdx.x & 63, wid = threadIdx.x >> 6;
    if (lane == 0) sb[wid] = s;
    __syncthreads();
    if (threadIdx.x == 0) t3[n] = sb[0] + sb[1] + sb[2] + sb[3];
}

// K4: fused triple GEMM: y = f@W.T + bias ; t1 = covg@(W^2).T ; t2 = (Wg*covg)@W.T
__global__ __launch_bounds__(256) void triple_gemm(
    const void* __restrict__ feat,
    const void* __restrict__ W,
    const void* __restrict__ bias,
    const float* __restrict__ ncov,            // C x A (f32 ws)
    const int* __restrict__ labels,
    const float* __restrict__ t3,
    void* __restrict__ out, size_t off_y,      // y region in d_out
    float* __restrict__ isda,                  // Nn x Cpad (f32 ws)
    const int* __restrict__ flag,
    int Nn, int C, int Cpad, int A, const void* ratio_p)
{
    __shared__ float sF[BK][BM + 1];
    __shared__ float sC[BK][BM + 1];
    __shared__ float sG[BK][BM + 1];
    __shared__ float sW[BK][BN + 1];

    int f32m = flag[0];
    int tid = threadIdx.x;
    int tx = tid & 15, ty = tid >> 4;
    int n0 = blockIdx.y * BM;
    int j0 = blockIdx.x * BN;

    float aY[4][2] = {};
    float aT1[4][2] = {};
    float aT2[4][2] = {};

    for (int k0 = 0; k0 < A; k0 += BK) {
        for (int e = tid; e < BM * BK; e += 256) {
            int r = e >> 4, c = e & 15;
            int n = n0 + r;
            int l = labels[n];
            size_t gk = (size_t)(k0 + c);
            float f  = ldv(feat, (size_t)n * A + gk, f32m);
            float cv = ncov[(size_t)l * A + gk];
            float wl = ldv(W, (size_t)l * A + gk, f32m);
            sF[c][r] = f;
            sC[c][r] = cv;
            sG[c][r] = wl * cv;
        }
        for (int e = tid; e < BN * BK; e += 256) {
            int r = e >> 4, c = e & 15;
            int j = j0 + r;
            sW[c][r] = (j < C) ? ldv(W, (size_t)j * A + (k0 + c), f32m) : 0.f;
        }
        __syncthreads();
        #pragma unroll
        for (int kk = 0; kk < BK; ++kk) {
            float fa[4], ca[4], ga[4];
            #pragma unroll
            for (int i = 0; i < 4; ++i) {
                int r = ty * 4 + i;
                fa[i] = sF[kk][r];
                ca[i] = sC[kk][r];
                ga[i] = sG[kk][r];
            }
            #pragma unroll
            for (int jj = 0; jj < 2; ++jj) {
                float w = sW[kk][tx + 16 * jj];
                float w2 = w * w;
                #pragma unroll
                for (int i = 0; i < 4; ++i) {
                    aY[i][jj]  += fa[i] * w;
                    aT1[i][jj] += ca[i] * w2;
                    aT2[i][jj] += ga[i] * w;
                }
            }
        }
        __syncthreads();
    }

    float ratio = decode_scalar(ratio_p);
    #pragma unroll
    for (int jj = 0; jj < 2; ++jj) {
        int j = j0 + tx + 16 * jj;
        if (j >= C) continue;
        float bj = ldv(bias, j, f32m);
        #pragma unroll
        for (int i = 0; i < 4; ++i) {
            int n = n0 + ty * 4 + i;
            float yv = aY[i][jj] + bj;
            stv(out, off_y + (size_t)n * C + j, yv, f32m);
            float sig = aT1[i][jj] - 2.f * aT2[i][jj] + t3[n];
            isda[(size_t)n * Cpad + j] = yv + 0.5f * ratio * sig;
        }
    }
}

// K5: per-row logsumexp + loss term
__global__ void row_loss(const float* __restrict__ isda, const int* __restrict__ labels,
                         float* __restrict__ rowloss, int C, int Cpad) {
    __shared__ float sb[4];
    __shared__ float bcast;
    int n = blockIdx.x;
    const float* row = isda + (size_t)n * Cpad;
    float m = -3.4e38f;
    for (int j = threadIdx.x; j < C; j += 256) m = fmaxf(m, row[j]);
    m = wave_max(m);
    int lane = threadIdx.x & 63, wid = threadIdx.x >> 6;
    if (lane == 0) sb[wid] = m;
    __syncthreads();
    if (threadIdx.x == 0)
        bcast = fmaxf(fmaxf(sb[0], sb[1]), fmaxf(sb[2], sb[3]));
    __syncthreads();
    m = bcast;
    __syncthreads();
    float s = 0.f;
    for (int j = threadIdx.x; j < C; j += 256) s += expf(row[j] - m);
    s = wave_sum(s);
    if (lane == 0) sb[wid] = s;
    __syncthreads();
    if (threadIdx.x == 0) {
        float tot = sb[0] + sb[1] + sb[2] + sb[3];
        rowloss[n] = m + logf(tot) - row[labels[n]];
    }
}

// K6: mean of rowloss -> loss scalar (element 0 of out)
__global__ void final_loss(const float* __restrict__ rowloss, void* __restrict__ out,
                           const int* __restrict__ flag, int Nn) {
    __shared__ float sb[4];
    int f32m = flag[0];
    float s = 0.f;
    for (int i = threadIdx.x; i < Nn; i += 256) s += rowloss[i];
    s = wave_sum(s);
    int lane = threadIdx.x & 63, wid = threadIdx.x >> 6;
    if (lane == 0) sb[wid] = s;
    __syncthreads();
    if (threadIdx.x == 0)
        stv(out, 0, (sb[0] + sb[1] + sb[2] + sb[3]) / (float)Nn, f32m);
}

extern "C" void kernel_launch(void* const* d_in, const int* in_sizes, int n_in,
                              void* d_out, int out_size, void* d_ws, size_t ws_size,
                              hipStream_t stream) {
    const void* feat   = d_in[0];
    const int*  labels = (const int*)d_in[1];
    const void* W      = d_in[2];
    const void* bias   = d_in[3];
    const void* ave    = d_in[4];
    const void* cov    = d_in[5];
    const void* amount = d_in[6];
    const void* ratiop = d_in[7];

    int NA = in_sizes[0];
    int Nn = in_sizes[1];
    int C  = in_sizes[3];
    int A  = NA / Nn;
    int CA = in_sizes[2];
    int Cpad = ((C + 255) / 256) * 256;

    size_t off_y   = 1;
    size_t off_ave = off_y + (size_t)Nn * C;
    size_t off_cov = off_ave + (size_t)CA;
    size_t off_amt = off_cov + (size_t)CA;

    float* ws = (float*)d_ws;
    int*   w_flag   = (int*)ws;                // 16 floats reserved
    float* w_counts = ws + 16;                 // 1024
    float* w_sums   = ws + 16 + 1024;          // CA
    float* w_sqs    = w_sums + CA;             // CA (becomes f32 ncov)
    float* w_t3     = w_sqs + CA;              // Nn
    float* w_rowls  = w_t3 + Nn;               // Nn
    float* w_isda   = w_rowls + Nn;            // Nn*Cpad

    hipMemsetAsync(ws, 0, (size_t)(16 + 1024 + 2 * (size_t)CA) * sizeof(float), stream);

    sniff_dtype<<<1, 256, 0, stream>>>(feat, NA < 65536 ? NA : 65536, w_flag);
    accum_stats<<<(NA + 255) / 256, 256, 0, stream>>>(feat, labels, w_sums, w_sqs, w_counts,
                                                      w_flag, Nn, A);
    finalize_stats<<<(CA + 255) / 256, 256, 0, stream>>>(w_sums, w_sqs, w_counts, ave, cov, amount,
                                                         d_out, off_ave, off_cov, off_amt,
                                                         w_flag, C, A);
    compute_t3<<<Nn, 256, 0, stream>>>(W, w_sqs, labels, w_t3, w_flag, A);
    dim3 g4((C + BN - 1) / BN, Nn / BM);
    triple_gemm<<<g4, 256, 0, stream>>>(feat, W, bias, w_sqs, labels, w_t3,
                                        d_out, off_y, w_isda, w_flag, Nn, C, Cpad, A, ratiop);
    row_loss<<<Nn, 256, 0, stream>>>(w_isda, labels, w_rowls, C, Cpad);
    final_loss<<<1, 256, 0, stream>>>(w_rowls, d_out, w_flag, Nn);
}

// Round 3
// 279.818 us; speedup vs baseline: 2.3481x; 2.3481x over previous
//
#include <hip/hip_runtime.h>
#include <hip/hip_bf16.h>

typedef short v8s __attribute__((ext_vector_type(8)));
typedef float v4f __attribute__((ext_vector_type(4)));

// ---- dual-dtype element access (flag: 0 = bf16, 1 = f32) ----
static __device__ __forceinline__ float ldv(const void* p, size_t i, int f32m) {
    if (f32m) return ((const float*)p)[i];
    return __bfloat162float(((const __hip_bfloat16*)p)[i]);
}
static __device__ __forceinline__ void stv(void* p, size_t i, float v, int f32m) {
    if (f32m) ((float*)p)[i] = v;
    else ((__hip_bfloat16*)p)[i] = __float2bfloat16(v);
}
static __device__ __forceinline__ unsigned short f2bu(float x) {
    __hip_bfloat16 h = __float2bfloat16(x);
    return *(unsigned short*)&h;
}
static __device__ __forceinline__ float bu2f(unsigned short u) {
    unsigned v = ((unsigned)u) << 16;
    return __uint_as_float(v);
}

// Robust scalar decode: handles int32, float32, or bf16-in-low-16 encodings.
static __device__ __forceinline__ float decode_scalar(const void* p) {
    unsigned u = *(const unsigned*)p;
    unsigned e32 = (u >> 23) & 0xff;
    if (e32 >= 97 && e32 <= 160) return __uint_as_float(u);
    unsigned lo = u & 0xffffu;
    unsigned e16 = (lo >> 7) & 0xff;
    if ((u >> 16) == 0 && e16 >= 97 && e16 <= 160)
        return __uint_as_float(lo << 16);
    return (float)(int)u;
}

__device__ __forceinline__ float wave_sum(float v) {
    #pragma unroll
    for (int o = 32; o > 0; o >>= 1) v += __shfl_down(v, o, 64);
    return v;
}
__device__ __forceinline__ float wave_max(float v) {
    #pragma unroll
    for (int o = 32; o > 0; o >>= 1) v = fmaxf(v, __shfl_down(v, o, 64));
    return v;
}

// K0: decide whether float inputs are bf16 (flag=0) or f32 (flag=1).
__global__ void sniff_dtype(const void* __restrict__ feat, int nSample, int* __restrict__ flag) {
    __shared__ int cnt;
    if (threadIdx.x == 0) cnt = 0;
    __syncthreads();
    const __hip_bfloat16* p = (const __hip_bfloat16*)feat;
    int local = 0;
    for (int i = threadIdx.x; i < nSample; i += 256) {
        float v = __bfloat162float(p[i]);
        if (!(fabsf(v) < 1e10f)) local++;
    }
    atomicAdd(&cnt, local);
    __syncthreads();
    if (threadIdx.x == 0) flag[0] = (cnt > 16) ? 1 : 0;
}

// K1: segment sums of x and x^2 per class, plus counts; also emit bf16 feat copy.
__global__ void accum_stats(const void* __restrict__ feat,
                            const int* __restrict__ labels,
                            float* __restrict__ sums, float* __restrict__ sqs,
                            float* __restrict__ counts,
                            unsigned short* __restrict__ featb,
                            const int* __restrict__ flag,
                            int Nn, int A) {
    int f32m = flag[0];
    int idx = blockIdx.x * 256 + threadIdx.x;
    if (idx >= Nn * A) return;
    int n = idx / A;
    int a = idx - n * A;
    int l = labels[n];
    float x = ldv(feat, idx, f32m);
    featb[idx] = f2bu(x);
    atomicAdd(&sums[(size_t)l * A + a], x);
    atomicAdd(&sqs[(size_t)l * A + a], x * x);
    if (a == 0) atomicAdd(&counts[l], 1.0f);
}

// K2: finalize stats -> outputs (ave/cov/amt) + f32 ncov (ws) + bf16 arrays
// Wb, W2b (=W^2), Cb (=ncov), Gb (=ncov*W) for the MFMA GEMM.
__global__ void finalize_stats(const float* __restrict__ sums, float* __restrict__ sqs_ncov,
                               const float* __restrict__ counts,
                               const void* __restrict__ ave,
                               const void* __restrict__ cov,
                               const void* __restrict__ amount,
                               const void* __restrict__ W,
                               void* __restrict__ out,
                               size_t off_ave, size_t off_cov, size_t off_amt,
                               unsigned short* __restrict__ Wb,
                               unsigned short* __restrict__ W2b,
                               unsigned short* __restrict__ Cb,
                               unsigned short* __restrict__ Gb,
                               const int* __restrict__ flag,
                               int C, int A) {
    int f32m = flag[0];
    int idx = blockIdx.x * 256 + threadIdx.x;
    if (idx >= C * A) return;
    int c = idx / A;
    int a = idx - c * A;
    float cnt = counts[c];
    float denom = cnt > 0.f ? cnt : 1.f;
    float mean = sums[idx] / denom;
    float var = (sqs_ncov[idx] - cnt * mean * mean) / denom;
    var = fmaxf(var, 0.f);
    float amt = ldv(amount, c, f32m);
    float tot = cnt + amt;
    float w = tot > 0.f ? (cnt / tot) : 0.f;   // nan_to_num(0/0) -> 0
    float av = ldv(ave, idx, f32m);
    float cv = ldv(cov, idx, f32m);
    float d = av - mean;
    float ncv = cv * (1.f - w) + var * w + w * (1.f - w) * d * d;
    float nav = av * (1.f - w) + mean * w;
    stv(out, off_cov + idx, ncv, f32m);
    stv(out, off_ave + idx, nav, f32m);
    sqs_ncov[idx] = ncv;
    float wv = ldv(W, idx, f32m);
    Wb[idx] = f2bu(wv);
    W2b[idx] = f2bu(wv * wv);
    Cb[idx] = f2bu(ncv);
    Gb[idx] = f2bu(ncv * wv);
    if (a == 0) stv(out, off_amt + c, amt + cnt, f32m);
}

// K3: t3[n] = sum_a W[l,a]^2 * ncov[l,a]  (bf16 W2b x f32 ncov)
__global__ void compute_t3(const unsigned short* __restrict__ W2b,
                           const float* __restrict__ ncov,
                           const int* __restrict__ labels,
                           float* __restrict__ t3, int A) {
    __shared__ float sb[4];
    int n = blockIdx.x;
    int l = labels[n];
    float s = 0.f;
    for (int a = threadIdx.x; a < A; a += 256) {
        s += bu2f(W2b[(size_t)l * A + a]) * ncov[(size_t)l * A + a];
    }
    s = wave_sum(s);
    int lane = threadIdx.x & 63, wid = threadIdx.x >> 6;
    if (lane == 0) sb[wid] = s;
    __syncthreads();
    if (threadIdx.x == 0) t3[n] = sb[0] + sb[1] + sb[2] + sb[3];
}

// K4: fused MFMA triple GEMM.
//   y   = feat @ W.T + bias
//   t1  = ncov[l] @ (W^2).T
//   t2  = (W[l]*ncov[l]) @ W.T
//   isda = y + 0.5*ratio*(t1 - 2*t2 + t3[n])
// Tile: 32 rows (n) x 64 cols (j); 4 waves; wave = 16x32 via 2 j-tiles of
// mfma_f32_16x16x32_bf16 with 3 accumulator chains sharing B-fragments.
__global__ __launch_bounds__(256) void triple_gemm_mfma(
    const unsigned short* __restrict__ featb,   // Nn x A bf16
    const unsigned short* __restrict__ Wb,      // C x A bf16
    const unsigned short* __restrict__ W2b,     // C x A bf16
    const unsigned short* __restrict__ Cb,      // C x A bf16 (ncov)
    const unsigned short* __restrict__ Gb,      // C x A bf16 (ncov*W)
    const void* __restrict__ bias,
    const int* __restrict__ labels,
    const float* __restrict__ t3,
    void* __restrict__ out, size_t off_y,
    float* __restrict__ isda,
    const int* __restrict__ flag,
    int Nn, int C, int Cpad, int A, const void* ratio_p)
{
    // LDS element offsets (ushort): F 0..1023, C 1024.., G 2048..,
    // W 3072..5119, W2 5120..7167. Each 16x32 fragment-tile = 512 elems,
    // stored in MFMA per-lane order: frag[lane][8] (lane-contiguous b128).
    __shared__ unsigned short sA[7168];
    __shared__ int sLab[32];

    int tid = threadIdx.x;
    int n0 = blockIdx.y * 32;
    int j0 = blockIdx.x * 64;

    if (tid < 32) sLab[tid] = labels[n0 + tid];

    int wv = tid >> 6, lane = tid & 63;
    int h = wv & 1;          // row-half (16 rows)
    int jq = wv >> 1;        // column pair (2 j-tiles of 16)
    int fo = lane * 8;       // fragment byte-offset/2 within a tile

    v4f aY0 = {}, aY1 = {}, aT10 = {}, aT11 = {}, aT20 = {}, aT21 = {};

    for (int k0 = 0; k0 < A; k0 += 32) {
        __syncthreads();     // protect LDS from previous iter's readers
        // stage 896 chunks of 16B: F/C/G 128 each, W/W2 256 each
        for (int e = tid; e < 896; e += 256) {
            if (e < 384) {
                int m = e >> 7;             // 0=F,1=C,2=G
                int r = (e >> 2) & 31;      // row within tile-pair
                int ch = e & 3;             // 8-elem k-chunk
                int row = (m == 0) ? (n0 + r) : sLab[r];
                const unsigned short* base = (m == 0) ? featb : (m == 1 ? Cb : Gb);
                int dst = m * 1024 + (r >> 4) * 512 + (ch * 16 + (r & 15)) * 8;
                *(v8s*)&sA[dst] = *(const v8s*)(base + (size_t)row * A + k0 + ch * 8);
            } else {
                int e2 = e - 384;
                int m = e2 >> 8;            // 0=W,1=W2
                int r = (e2 >> 2) & 63;
                int ch = e2 & 3;
                int j = j0 + r;
                int dst = 3072 + m * 2048 + (r >> 4) * 512 + (ch * 16 + (r & 15)) * 8;
                if (j < C) {
                    const unsigned short* base = m ? W2b : Wb;
                    *(v8s*)&sA[dst] = *(const v8s*)(base + (size_t)j * A + k0 + ch * 8);
                } else {
                    v8s z = {0, 0, 0, 0, 0, 0, 0, 0};
                    *(v8s*)&sA[dst] = z;
                }
            }
        }
        __syncthreads();

        v8s f  = *(v8s*)&sA[0    + h * 512 + fo];
        v8s c  = *(v8s*)&sA[1024 + h * 512 + fo];
        v8s g  = *(v8s*)&sA[2048 + h * 512 + fo];
        v8s w0 = *(v8s*)&sA[3072 + (jq * 2 + 0) * 512 + fo];
        v8s w1 = *(v8s*)&sA[3072 + (jq * 2 + 1) * 512 + fo];
        v8s q0 = *(v8s*)&sA[5120 + (jq * 2 + 0) * 512 + fo];
        v8s q1 = *(v8s*)&sA[5120 + (jq * 2 + 1) * 512 + fo];

        aY0  = __builtin_amdgcn_mfma_f32_16x16x32_bf16(f, w0, aY0, 0, 0, 0);
        aY1  = __builtin_amdgcn_mfma_f32_16x16x32_bf16(f, w1, aY1, 0, 0, 0);
        aT10 = __builtin_amdgcn_mfma_f32_16x16x32_bf16(c, q0, aT10, 0, 0, 0);
        aT11 = __builtin_amdgcn_mfma_f32_16x16x32_bf16(c, q1, aT11, 0, 0, 0);
        aT20 = __builtin_amdgcn_mfma_f32_16x16x32_bf16(g, w0, aT20, 0, 0, 0);
        aT21 = __builtin_amdgcn_mfma_f32_16x16x32_bf16(g, w1, aT21, 0, 0, 0);
    }

    // Epilogue. C/D layout: col = lane&15, row = (lane>>4)*4 + reg.
    int f32m = flag[0];
    float ratio = decode_scalar(ratio_p);
    int quad = lane >> 4;
    int colb = lane & 15;

    #pragma unroll
    for (int t = 0; t < 2; ++t) {
        int j = j0 + (jq * 2 + t) * 16 + colb;
        if (j >= C) continue;
        float bj = ldv(bias, j, f32m);
        v4f y  = t ? aY1  : aY0;
        v4f t1 = t ? aT11 : aT10;
        v4f t2 = t ? aT21 : aT20;
        #pragma unroll
        for (int r = 0; r < 4; ++r) {
            int n = n0 + h * 16 + quad * 4 + r;
            float yv = y[r] + bj;
            stv(out, off_y + (size_t)n * C + j, yv, f32m);
            float sig = t1[r] - 2.f * t2[r] + t3[n];
            isda[(size_t)n * Cpad + j] = yv + 0.5f * ratio * sig;
        }
    }
}

// K5: per-row logsumexp + loss term
__global__ void row_loss(const float* __restrict__ isda, const int* __restrict__ labels,
                         float* __restrict__ rowloss, int C, int Cpad) {
    __shared__ float sb[4];
    __shared__ float bcast;
    int n = blockIdx.x;
    const float* row = isda + (size_t)n * Cpad;
    float m = -3.4e38f;
    for (int j = threadIdx.x; j < C; j += 256) m = fmaxf(m, row[j]);
    m = wave_max(m);
    int lane = threadIdx.x & 63, wid = threadIdx.x >> 6;
    if (lane == 0) sb[wid] = m;
    __syncthreads();
    if (threadIdx.x == 0)
        bcast = fmaxf(fmaxf(sb[0], sb[1]), fmaxf(sb[2], sb[3]));
    __syncthreads();
    m = bcast;
    __syncthreads();
    float s = 0.f;
    for (int j = threadIdx.x; j < C; j += 256) s += expf(row[j] - m);
    s = wave_sum(s);
    if (lane == 0) sb[wid] = s;
    __syncthreads();
    if (threadIdx.x == 0) {
        float tot = sb[0] + sb[1] + sb[2] + sb[3];
        rowloss[n] = m + logf(tot) - row[labels[n]];
    }
}

// K6: mean of rowloss -> loss scalar (element 0 of out)
__global__ void final_loss(const float* __restrict__ rowloss, void* __restrict__ out,
                           const int* __restrict__ flag, int Nn) {
    __shared__ float sb[4];
    int f32m = flag[0];
    float s = 0.f;
    for (int i = threadIdx.x; i < Nn; i += 256) s += rowloss[i];
    s = wave_sum(s);
    int lane = threadIdx.x & 63, wid = threadIdx.x >> 6;
    if (lane == 0) sb[wid] = s;
    __syncthreads();
    if (threadIdx.x == 0)
        stv(out, 0, (sb[0] + sb[1] + sb[2] + sb[3]) / (float)Nn, f32m);
}

extern "C" void kernel_launch(void* const* d_in, const int* in_sizes, int n_in,
                              void* d_out, int out_size, void* d_ws, size_t ws_size,
                              hipStream_t stream) {
    const void* feat   = d_in[0];
    const int*  labels = (const int*)d_in[1];
    const void* W      = d_in[2];
    const void* bias   = d_in[3];
    const void* ave    = d_in[4];
    const void* cov    = d_in[5];
    const void* amount = d_in[6];
    const void* ratiop = d_in[7];

    int NA = in_sizes[0];
    int Nn = in_sizes[1];
    int C  = in_sizes[3];
    int A  = NA / Nn;
    int CA = in_sizes[2];
    int Cpad = ((C + 255) / 256) * 256;

    size_t off_y   = 1;
    size_t off_ave = off_y + (size_t)Nn * C;
    size_t off_cov = off_ave + (size_t)CA;
    size_t off_amt = off_cov + (size_t)CA;

    float* ws = (float*)d_ws;
    int*   w_flag   = (int*)ws;                // 16 floats reserved
    float* w_counts = ws + 16;                 // 1024
    float* w_sums   = ws + 16 + 1024;          // CA
    float* w_sqs    = w_sums + CA;             // CA (becomes f32 ncov)
    float* w_t3     = w_sqs + CA;              // Nn (pad to 512-mult below anyway)
    float* w_rowls  = w_t3 + Nn;               // Nn
    float* w_isda   = w_rowls + Nn;            // Nn*Cpad
    unsigned short* w_featb = (unsigned short*)(w_isda + (size_t)Nn * Cpad);  // NA
    unsigned short* w_Wb    = w_featb + NA;    // CA
    unsigned short* w_W2b   = w_Wb + CA;       // CA
    unsigned short* w_Cb    = w_W2b + CA;      // CA
    unsigned short* w_Gb    = w_Cb + CA;       // CA

    hipMemsetAsync(ws, 0, (size_t)(16 + 1024 + 2 * (size_t)CA) * sizeof(float), stream);

    sniff_dtype<<<1, 256, 0, stream>>>(feat, NA < 65536 ? NA : 65536, w_flag);
    accum_stats<<<(NA + 255) / 256, 256, 0, stream>>>(feat, labels, w_sums, w_sqs, w_counts,
                                                      w_featb, w_flag, Nn, A);
    finalize_stats<<<(CA + 255) / 256, 256, 0, stream>>>(w_sums, w_sqs, w_counts, ave, cov, amount,
                                                         W, d_out, off_ave, off_cov, off_amt,
                                                         w_Wb, w_W2b, w_Cb, w_Gb, w_flag, C, A);
    compute_t3<<<Nn, 256, 0, stream>>>(w_W2b, w_sqs, labels, w_t3, A);
    dim3 g4((C + 63) / 64, Nn / 32);
    triple_gemm_mfma<<<g4, 256, 0, stream>>>(w_featb, w_Wb, w_W2b, w_Cb, w_Gb,
                                             bias, labels, w_t3,
                                             d_out, off_y, w_isda, w_flag,
                                             Nn, C, Cpad, A, ratiop);
    row_loss<<<Nn, 256, 0, stream>>>(w_isda, labels, w_rowls, C, Cpad);
    final_loss<<<1, 256, 0, stream>>>(w_rowls, d_out, w_flag, Nn);
}

// Round 4
// 163.686 us; speedup vs baseline: 4.0140x; 1.7095x over previous
//
#include <hip/hip_runtime.h>
#include <hip/hip_bf16.h>

typedef short v8s __attribute__((ext_vector_type(8)));
typedef float v4f __attribute__((ext_vector_type(4)));

#define KSPLIT 4

// ---- dual-dtype element access (f32m: 0 = bf16, 1 = f32) ----
static __device__ __forceinline__ float ldv(const void* p, size_t i, int f32m) {
    if (f32m) return ((const float*)p)[i];
    return __bfloat162float(((const __hip_bfloat16*)p)[i]);
}
static __device__ __forceinline__ void stv(void* p, size_t i, float v, int f32m) {
    if (f32m) ((float*)p)[i] = v;
    else ((__hip_bfloat16*)p)[i] = __float2bfloat16(v);
}
static __device__ __forceinline__ unsigned short f2bu(float x) {
    __hip_bfloat16 h = __float2bfloat16(x);
    return *(unsigned short*)&h;
}

// Robust scalar decode: handles int32, float32, or bf16-in-low-16 encodings.
static __device__ __forceinline__ float decode_scalar(const void* p) {
    unsigned u = *(const unsigned*)p;
    unsigned e32 = (u >> 23) & 0xff;
    if (e32 >= 97 && e32 <= 160) return __uint_as_float(u);
    unsigned lo = u & 0xffffu;
    unsigned e16 = (lo >> 7) & 0xff;
    if ((u >> 16) == 0 && e16 >= 97 && e16 <= 160)
        return __uint_as_float(lo << 16);
    return (float)(int)u;
}

// Per-block dtype sniff: interpret first 256 halves of feat as bf16.
// True bf16 N(0,1): all finite & small. f32 misread: ~37% of lo-halves huge.
// Deterministic (same data every block). Requires blockDim.x >= 256 & all
// threads reaching it (contains a barrier).
static __device__ __forceinline__ int block_sniff(const void* feat) {
    const __hip_bfloat16* p = (const __hip_bfloat16*)feat;
    float v = __bfloat162float(p[threadIdx.x & 255]);
    int bad = !(fabsf(v) < 1e10f);
    return __syncthreads_or(bad) ? 1 : 0;
}

__device__ __forceinline__ float wave_sum(float v) {
    #pragma unroll
    for (int o = 32; o > 0; o >>= 1) v += __shfl_down(v, o, 64);
    return v;
}
__device__ __forceinline__ float wave_max(float v) {
    #pragma unroll
    for (int o = 32; o > 0; o >>= 1) v = fmaxf(v, __shfl_down(v, o, 64));
    return v;
}

// async global->LDS, 16B per lane, LDS dst = wave-uniform base + lane*16
static __device__ __forceinline__ void ld16(unsigned short* lds, const unsigned short* g) {
    __builtin_amdgcn_global_load_lds(
        (const __attribute__((address_space(1))) unsigned int*)g,
        (__attribute__((address_space(3))) unsigned int*)lds,
        16, 0, 0);
}

// K1: segment sums of x and x^2 per class + counts; emit bf16 feat copy.
__global__ __launch_bounds__(256) void accum_stats(
        const void* __restrict__ feat, const int* __restrict__ labels,
        float* __restrict__ sums, float* __restrict__ sqs,
        float* __restrict__ counts, unsigned short* __restrict__ featb,
        int Nn, int A) {
    int f32m = block_sniff(feat);
    int idx = blockIdx.x * 256 + threadIdx.x;
    if (idx >= Nn * A) return;
    int n = idx / A;
    int a = idx - n * A;
    int l = labels[n];
    float x = ldv(feat, idx, f32m);
    featb[idx] = f2bu(x);
    atomicAdd(&sums[(size_t)l * A + a], x);
    atomicAdd(&sqs[(size_t)l * A + a], x * x);
    if (a == 0) atomicAdd(&counts[l], 1.0f);
}

// K2: finalize stats -> outputs (ave/cov/amt), bf16 GEMM operands
// (Wb, W2b, Cb=ncov, Gb=ncov*W), and per-class T3c[c] = sum_a W^2*ncov (f32).
// Each block covers 256 consecutive a's of ONE class c (requires A%256==0).
__global__ __launch_bounds__(256) void finalize_stats(
        const float* __restrict__ sums, const float* __restrict__ sqs,
        const float* __restrict__ counts,
        const void* __restrict__ ave, const void* __restrict__ cov,
        const void* __restrict__ amount, const void* __restrict__ W,
        const void* __restrict__ feat,
        void* __restrict__ out, size_t off_ave, size_t off_cov, size_t off_amt,
        unsigned short* __restrict__ Wb, unsigned short* __restrict__ W2b,
        unsigned short* __restrict__ Cb, unsigned short* __restrict__ Gb,
        float* __restrict__ T3c,
        int C, int A) {
    __shared__ float sb[4];
    int f32m = block_sniff(feat);
    int idx = blockIdx.x * 256 + threadIdx.x;
    int c = idx / A;
    int a = idx - c * A;
    float cnt = counts[c];
    float denom = cnt > 0.f ? cnt : 1.f;
    float mean = sums[idx] / denom;
    float var = (sqs[idx] - cnt * mean * mean) / denom;
    var = fmaxf(var, 0.f);
    float amt = ldv(amount, c, f32m);
    float tot = cnt + amt;
    float w = tot > 0.f ? (cnt / tot) : 0.f;   // nan_to_num(0/0) -> 0
    float av = ldv(ave, idx, f32m);
    float cv = ldv(cov, idx, f32m);
    float d = av - mean;
    float ncv = cv * (1.f - w) + var * w + w * (1.f - w) * d * d;
    float nav = av * (1.f - w) + mean * w;
    stv(out, off_cov + idx, ncv, f32m);
    stv(out, off_ave + idx, nav, f32m);
    float wv = ldv(W, idx, f32m);
    Wb[idx] = f2bu(wv);
    W2b[idx] = f2bu(wv * wv);
    Cb[idx] = f2bu(ncv);
    Gb[idx] = f2bu(ncv * wv);
    if (a == 0) stv(out, off_amt + c, amt + cnt, f32m);
    // block-reduce W^2 * ncov -> one atomic per block into T3c[c]
    float s = wave_sum(wv * wv * ncv);
    int lane = threadIdx.x & 63, wid = threadIdx.x >> 6;
    if (lane == 0) sb[wid] = s;
    __syncthreads();
    if (threadIdx.x == 0) atomicAdd(&T3c[c], sb[0] + sb[1] + sb[2] + sb[3]);
}

// K3: split-K fused MFMA triple GEMM. Tile 64n x 64j, K-slice A/KSPLIT.
// 4 waves; wave w: rows [w*16, w*16+16) x all 64 j. 12 MFMAs/iter.
// Staging: 5 global_load_lds(16B) per wave per iter (F,C,G + W,W2 tile w),
// fragment-ordered LDS (lane-contiguous). Partials: f32 atomicAdd.
__global__ __launch_bounds__(256) void triple_gemm_mfma(
        const unsigned short* __restrict__ featb,
        const unsigned short* __restrict__ Wb,
        const unsigned short* __restrict__ W2b,
        const unsigned short* __restrict__ Cb,
        const unsigned short* __restrict__ Gb,
        const int* __restrict__ labels,
        float* __restrict__ accY, float* __restrict__ accT1, float* __restrict__ accT2,
        int Cpad, int A) {
    __shared__ unsigned short sA[10240];   // F:0 C:2048 G:4096 W:6144 W2:8192
    __shared__ int sLab[64];
    int tid = threadIdx.x, wv = tid >> 6, lane = tid & 63;
    int n0 = blockIdx.y * 64, j0 = blockIdx.x * 64;
    int kslice = A / KSPLIT;
    int k0 = blockIdx.z * kslice;
    if (tid < 64) sLab[tid] = labels[n0 + tid];
    __syncthreads();

    int r = lane & 15, q = lane >> 4;
    int fr = wv * 16 + r;     // row (A-side) / col (B-side) this lane stages
    const unsigned short* pF = featb + (size_t)(n0 + fr) * A + k0 + q * 8;
    int lab = sLab[fr];
    const unsigned short* pC = Cb + (size_t)lab * A + k0 + q * 8;
    const unsigned short* pG = Gb + (size_t)lab * A + k0 + q * 8;
    const unsigned short* pW = Wb + (size_t)(j0 + fr) * A + k0 + q * 8;
    const unsigned short* pQ = W2b + (size_t)(j0 + fr) * A + k0 + q * 8;
    unsigned short* dF = &sA[0    + wv * 512];
    unsigned short* dC = &sA[2048 + wv * 512];
    unsigned short* dG = &sA[4096 + wv * 512];
    unsigned short* dW = &sA[6144 + wv * 512];
    unsigned short* dQ = &sA[8192 + wv * 512];

    v4f aY[4] = {{0,0,0,0},{0,0,0,0},{0,0,0,0},{0,0,0,0}};
    v4f aT1[4] = {{0,0,0,0},{0,0,0,0},{0,0,0,0},{0,0,0,0}};
    v4f aT2[4] = {{0,0,0,0},{0,0,0,0},{0,0,0,0},{0,0,0,0}};

    for (int kk = 0; kk < kslice; kk += 32) {
        ld16(dF, pF); ld16(dC, pC); ld16(dG, pG); ld16(dW, pW); ld16(dQ, pQ);
        pF += 32; pC += 32; pG += 32; pW += 32; pQ += 32;
        __syncthreads();   // drains the LDS-DMA (vmcnt) + joins waves
        v8s f = *(v8s*)&sA[0    + wv * 512 + lane * 8];
        v8s c = *(v8s*)&sA[2048 + wv * 512 + lane * 8];
        v8s g = *(v8s*)&sA[4096 + wv * 512 + lane * 8];
        #pragma unroll
        for (int t = 0; t < 4; ++t) {
            v8s w  = *(v8s*)&sA[6144 + t * 512 + lane * 8];
            v8s w2 = *(v8s*)&sA[8192 + t * 512 + lane * 8];
            aY[t]  = __builtin_amdgcn_mfma_f32_16x16x32_bf16(f, w,  aY[t],  0, 0, 0);
            aT1[t] = __builtin_amdgcn_mfma_f32_16x16x32_bf16(c, w2, aT1[t], 0, 0, 0);
            aT2[t] = __builtin_amdgcn_mfma_f32_16x16x32_bf16(g, w,  aT2[t], 0, 0, 0);
        }
        __syncthreads();   // readers done before next iter's DMA overwrites
    }

    // C/D layout: col = lane&15, row = (lane>>4)*4 + reg (verified R3).
    int quad = lane >> 4, colb = lane & 15;
    #pragma unroll
    for (int t = 0; t < 4; ++t) {
        int j = j0 + t * 16 + colb;        // may land in pad j>=C: harmless
        #pragma unroll
        for (int rr = 0; rr < 4; ++rr) {
            int n = n0 + wv * 16 + quad * 4 + rr;
            size_t idx = (size_t)n * Cpad + j;
            atomicAdd(&accY[idx],  aY[t][rr]);
            atomicAdd(&accT1[idx], aT1[t][rr]);
            atomicAdd(&accT2[idx], aT2[t][rr]);
        }
    }
}

// K4: epilogue: y = accY + bias (store to out), isda = y + 0.5*ratio*sig.
__global__ __launch_bounds__(256) void epilogue(
        const float* __restrict__ accY, const float* __restrict__ accT1,
        const float* __restrict__ accT2, const float* __restrict__ T3c,
        const void* __restrict__ bias, const void* __restrict__ feat,
        const int* __restrict__ labels,
        void* __restrict__ out, size_t off_y,
        float* __restrict__ isda, int C, int Cpad, const void* ratio_p) {
    int f32m = block_sniff(feat);
    int n = blockIdx.y;
    int j = blockIdx.x * 256 + threadIdx.x;
    if (j >= C) return;
    float ratio = decode_scalar(ratio_p);
    float t3 = T3c[labels[n]];
    size_t idx = (size_t)n * Cpad + j;
    float yv = accY[idx] + ldv(bias, j, f32m);
    stv(out, off_y + (size_t)n * C + j, yv, f32m);
    isda[idx] = yv + 0.5f * ratio * (accT1[idx] - 2.f * accT2[idx] + t3);
}

// K5: per-row logsumexp + loss term
__global__ __launch_bounds__(256) void row_loss(
        const float* __restrict__ isda, const int* __restrict__ labels,
        float* __restrict__ rowloss, int C, int Cpad) {
    __shared__ float sb[4];
    __shared__ float bcast;
    int n = blockIdx.x;
    const float* row = isda + (size_t)n * Cpad;
    float m = -3.4e38f;
    for (int j = threadIdx.x; j < C; j += 256) m = fmaxf(m, row[j]);
    m = wave_max(m);
    int lane = threadIdx.x & 63, wid = threadIdx.x >> 6;
    if (lane == 0) sb[wid] = m;
    __syncthreads();
    if (threadIdx.x == 0)
        bcast = fmaxf(fmaxf(sb[0], sb[1]), fmaxf(sb[2], sb[3]));
    __syncthreads();
    m = bcast;
    __syncthreads();
    float s = 0.f;
    for (int j = threadIdx.x; j < C; j += 256) s += expf(row[j] - m);
    s = wave_sum(s);
    if (lane == 0) sb[wid] = s;
    __syncthreads();
    if (threadIdx.x == 0) {
        float tot = sb[0] + sb[1] + sb[2] + sb[3];
        rowloss[n] = m + logf(tot) - row[labels[n]];
    }
}

// K6: mean of rowloss -> loss scalar (element 0 of out)
__global__ __launch_bounds__(256) void final_loss(
        const float* __restrict__ rowloss, void* __restrict__ out,
        const void* __restrict__ feat, int Nn) {
    __shared__ float sb[4];
    int f32m = block_sniff(feat);
    float s = 0.f;
    for (int i = threadIdx.x; i < Nn; i += 256) s += rowloss[i];
    s = wave_sum(s);
    int lane = threadIdx.x & 63, wid = threadIdx.x >> 6;
    if (lane == 0) sb[wid] = s;
    __syncthreads();
    if (threadIdx.x == 0)
        stv(out, 0, (sb[0] + sb[1] + sb[2] + sb[3]) / (float)Nn, f32m);
}

extern "C" void kernel_launch(void* const* d_in, const int* in_sizes, int n_in,
                              void* d_out, int out_size, void* d_ws, size_t ws_size,
                              hipStream_t stream) {
    const void* feat   = d_in[0];
    const int*  labels = (const int*)d_in[1];
    const void* W      = d_in[2];
    const void* bias   = d_in[3];
    const void* ave    = d_in[4];
    const void* cov    = d_in[5];
    const void* amount = d_in[6];
    const void* ratiop = d_in[7];

    int NA = in_sizes[0];                  // N*A
    int Nn = in_sizes[1];                  // 512
    int C  = in_sizes[3];                  // 1000
    int A  = NA / Nn;                      // 2048
    int CA = in_sizes[2];                  // C*A
    int Cpad = ((C + 255) / 256) * 256;    // 1024
    size_t NC = (size_t)Nn * Cpad;

    size_t off_y   = 1;
    size_t off_ave = off_y + (size_t)Nn * C;
    size_t off_cov = off_ave + (size_t)CA;
    size_t off_amt = off_cov + (size_t)CA;

    float* ws = (float*)d_ws;
    float* w_counts = ws;                      // 1024
    float* w_T3c    = ws + 1024;               // 1024
    float* w_sums   = ws + 2048;               // CA
    float* w_sqs    = w_sums + CA;             // CA
    float* w_accY   = w_sqs + CA;              // NC
    float* w_accT1  = w_accY + NC;             // NC
    float* w_accT2  = w_accT1 + NC;            // NC
    float* w_isda   = w_accT2 + NC;            // NC
    float* w_rowls  = w_isda + NC;             // Nn (pad 1024)
    unsigned short* w_featb = (unsigned short*)(w_rowls + 1024);  // NA
    unsigned short* w_Wb    = w_featb + NA;    // CA
    unsigned short* w_W2b   = w_Wb + CA;       // CA
    unsigned short* w_Cb    = w_W2b + CA;      // CA
    unsigned short* w_Gb    = w_Cb + CA;       // CA

    // zero: counts, T3c, sums, sqs, accY/T1/T2
    hipMemsetAsync(ws, 0, (size_t)(2048 + 2 * (size_t)CA + 3 * NC) * sizeof(float), stream);

    accum_stats<<<(NA + 255) / 256, 256, 0, stream>>>(feat, labels, w_sums, w_sqs,
                                                      w_counts, w_featb, Nn, A);
    finalize_stats<<<(CA + 255) / 256, 256, 0, stream>>>(
        w_sums, w_sqs, w_counts, ave, cov, amount, W, feat,
        d_out, off_ave, off_cov, off_amt,
        w_Wb, w_W2b, w_Cb, w_Gb, w_T3c, C, A);
    dim3 g3(Cpad / 64, Nn / 64, KSPLIT);
    triple_gemm_mfma<<<g3, 256, 0, stream>>>(w_featb, w_Wb, w_W2b, w_Cb, w_Gb,
                                             labels, w_accY, w_accT1, w_accT2, Cpad, A);
    dim3 g4((C + 255) / 256, Nn);
    epilogue<<<g4, 256, 0, stream>>>(w_accY, w_accT1, w_accT2, w_T3c, bias, feat,
                                     labels, d_out, off_y, w_isda, C, Cpad, ratiop);
    row_loss<<<Nn, 256, 0, stream>>>(w_isda, labels, w_rowls, C, Cpad);
    final_loss<<<1, 256, 0, stream>>>(w_rowls, d_out, feat, Nn);
}

// Round 5
// 141.878 us; speedup vs baseline: 4.6309x; 1.1537x over previous
//
#include <hip/hip_runtime.h>
#include <hip/hip_bf16.h>

typedef short v8s __attribute__((ext_vector_type(8)));
typedef float v4f __attribute__((ext_vector_type(4)));

#define KSPLIT 4

// ---- dual-dtype element access (f32m: 0 = bf16, 1 = f32) ----
static __device__ __forceinline__ float ldv(const void* p, size_t i, int f32m) {
    if (f32m) return ((const float*)p)[i];
    return __bfloat162float(((const __hip_bfloat16*)p)[i]);
}
static __device__ __forceinline__ void stv(void* p, size_t i, float v, int f32m) {
    if (f32m) ((float*)p)[i] = v;
    else ((__hip_bfloat16*)p)[i] = __float2bfloat16(v);
}
static __device__ __forceinline__ unsigned short f2bu(float x) {
    __hip_bfloat16 h = __float2bfloat16(x);
    return *(unsigned short*)&h;
}
static __device__ __forceinline__ float bu2f(unsigned short u) {
    return __uint_as_float(((unsigned)u) << 16);
}

// Robust scalar decode: handles int32, float32, or bf16-in-low-16 encodings.
static __device__ __forceinline__ float decode_scalar(const void* p) {
    unsigned u = *(const unsigned*)p;
    unsigned e32 = (u >> 23) & 0xff;
    if (e32 >= 97 && e32 <= 160) return __uint_as_float(u);
    unsigned lo = u & 0xffffu;
    unsigned e16 = (lo >> 7) & 0xff;
    if ((u >> 16) == 0 && e16 >= 97 && e16 <= 160)
        return __uint_as_float(lo << 16);
    return (float)(int)u;
}

// Per-block dtype sniff (deterministic; contains a barrier — call unconditionally).
static __device__ __forceinline__ int block_sniff(const void* feat) {
    const __hip_bfloat16* p = (const __hip_bfloat16*)feat;
    float v = __bfloat162float(p[threadIdx.x & 255]);
    int bad = !(fabsf(v) < 1e10f);
    return __syncthreads_or(bad) ? 1 : 0;
}

__device__ __forceinline__ float wave_sum(float v) {
    #pragma unroll
    for (int o = 32; o > 0; o >>= 1) v += __shfl_down(v, o, 64);
    return v;
}
__device__ __forceinline__ float wave_max(float v) {
    #pragma unroll
    for (int o = 32; o > 0; o >>= 1) v = fmaxf(v, __shfl_down(v, o, 64));
    return v;
}

// async global->LDS, 16B per lane, LDS dst = wave-uniform base + lane*16
static __device__ __forceinline__ void ld16(unsigned short* lds, const unsigned short* g) {
    __builtin_amdgcn_global_load_lds(
        (const __attribute__((address_space(1))) unsigned int*)g,
        (__attribute__((address_space(3))) unsigned int*)lds,
        16, 0, 0);
}

// K1: single-block counting sort of labels -> counts[c], offs[c] (exclusive),
// rows[] (row indices grouped by class). LDS only; no global zero-init needed.
__global__ __launch_bounds__(1024) void count_sort(
        const int* __restrict__ labels, int* __restrict__ counts,
        int* __restrict__ offs, int* __restrict__ rows, int Nn, int C) {
    __shared__ int h[1024];
    __shared__ int o[1024];
    __shared__ int cur[1024];
    int tid = threadIdx.x;
    h[tid] = 0;
    __syncthreads();
    for (int i = tid; i < Nn; i += 1024) atomicAdd(&h[labels[i]], 1);
    __syncthreads();
    o[tid] = h[tid];
    __syncthreads();
    for (int d = 1; d < 1024; d <<= 1) {
        int v = (tid >= d) ? o[tid - d] : 0;
        __syncthreads();
        o[tid] += v;
        __syncthreads();
    }
    int excl = o[tid] - h[tid];
    counts[tid] = h[tid];
    offs[tid] = excl;
    cur[tid] = excl;
    __syncthreads();
    for (int i = tid; i < Nn; i += 1024) {
        int pos = atomicAdd(&cur[labels[i]], 1);
        rows[pos] = i;
    }
}

// K2: feat -> bf16 copy, 8 elems/thread (requires total % 2048 == 0).
__global__ __launch_bounds__(256) void prep(
        const void* __restrict__ feat, unsigned short* __restrict__ featb, int total) {
    int f32m = block_sniff(feat);
    int i = (blockIdx.x * 256 + threadIdx.x) * 8;
    if (i >= total) return;
    if (f32m) {
        const float* f = (const float*)feat + i;
        unsigned short r[8];
        #pragma unroll
        for (int u = 0; u < 8; ++u) r[u] = f2bu(f[u]);
        *(v8s*)(featb + i) = *(v8s*)r;
    } else {
        *(v8s*)(featb + i) = *(const v8s*)((const unsigned short*)feat + i);
    }
}

// K3: finalize stats. Block = (class c = blockIdx.y, 256-col chunk = blockIdx.x).
// Computes mean/var by gathering this class's rows from featb (CSR), then
// new_ave/new_cov/new_amount outputs + bf16 GEMM operands + T3 partials.
__global__ __launch_bounds__(256) void finalize_stats(
        const unsigned short* __restrict__ featb,
        const int* __restrict__ counts, const int* __restrict__ offs,
        const int* __restrict__ rows,
        const void* __restrict__ ave, const void* __restrict__ cov,
        const void* __restrict__ amount, const void* __restrict__ W,
        const void* __restrict__ feat,
        void* __restrict__ out, size_t off_ave, size_t off_cov, size_t off_amt,
        unsigned short* __restrict__ Wb, unsigned short* __restrict__ W2b,
        unsigned short* __restrict__ Cb, unsigned short* __restrict__ Gb,
        float* __restrict__ T3p, int A, int A8) {
    __shared__ float sb[4];
    int f32m = block_sniff(feat);
    int c = blockIdx.y;
    int a = blockIdx.x * 256 + threadIdx.x;
    size_t idx = (size_t)c * A + a;
    int cnti = counts[c];
    int start = offs[c];
    float s1 = 0.f, s2 = 0.f;
    for (int i = 0; i < cnti; ++i) {
        float x = bu2f(featb[(size_t)rows[start + i] * A + a]);
        s1 += x;
        s2 += x * x;
    }
    float cnt = (float)cnti;
    float denom = cnti > 0 ? cnt : 1.f;
    float mean = s1 / denom;
    float var = fmaxf((s2 - cnt * mean * mean) / denom, 0.f);
    float amt = ldv(amount, c, f32m);
    float tot = cnt + amt;
    float w = tot > 0.f ? (cnt / tot) : 0.f;   // nan_to_num(0/0) -> 0
    float av = ldv(ave, idx, f32m);
    float cv = ldv(cov, idx, f32m);
    float d = av - mean;
    float ncv = cv * (1.f - w) + var * w + w * (1.f - w) * d * d;
    float nav = av * (1.f - w) + mean * w;
    stv(out, off_cov + idx, ncv, f32m);
    stv(out, off_ave + idx, nav, f32m);
    float wv = ldv(W, idx, f32m);
    Wb[idx] = f2bu(wv);
    W2b[idx] = f2bu(wv * wv);
    Cb[idx] = f2bu(ncv);
    Gb[idx] = f2bu(ncv * wv);
    if (a == 0) stv(out, off_amt + c, amt + cnt, f32m);
    // T3 partial for this (c, chunk): sum of W^2 * ncov
    float s = wave_sum(wv * wv * ncv);
    int lane = threadIdx.x & 63, wid = threadIdx.x >> 6;
    if (lane == 0) sb[wid] = s;
    __syncthreads();
    if (threadIdx.x == 0) T3p[(size_t)c * A8 + blockIdx.x] = sb[0] + sb[1] + sb[2] + sb[3];
}

// K4: split-K fused MFMA triple GEMM -> per-slice partials (no atomics).
__global__ __launch_bounds__(256) void triple_gemm_mfma(
        const unsigned short* __restrict__ featb,
        const unsigned short* __restrict__ Wb,
        const unsigned short* __restrict__ W2b,
        const unsigned short* __restrict__ Cb,
        const unsigned short* __restrict__ Gb,
        const int* __restrict__ labels,
        float* __restrict__ partY, float* __restrict__ partT1, float* __restrict__ partT2,
        int Cpad, int A, size_t NC) {
    __shared__ unsigned short sA[10240];   // F:0 C:2048 G:4096 W:6144 W2:8192
    __shared__ int sLab[64];
    int tid = threadIdx.x, wv = tid >> 6, lane = tid & 63;
    int n0 = blockIdx.y * 64, j0 = blockIdx.x * 64;
    int kslice = A / KSPLIT;
    int k0 = blockIdx.z * kslice;
    if (tid < 64) sLab[tid] = labels[n0 + tid];
    __syncthreads();

    int r = lane & 15, q = lane >> 4;
    int fr = wv * 16 + r;
    const unsigned short* pF = featb + (size_t)(n0 + fr) * A + k0 + q * 8;
    int lab = sLab[fr];
    const unsigned short* pC = Cb + (size_t)lab * A + k0 + q * 8;
    const unsigned short* pG = Gb + (size_t)lab * A + k0 + q * 8;
    const unsigned short* pW = Wb + (size_t)(j0 + fr) * A + k0 + q * 8;
    const unsigned short* pQ = W2b + (size_t)(j0 + fr) * A + k0 + q * 8;
    unsigned short* dF = &sA[0    + wv * 512];
    unsigned short* dC = &sA[2048 + wv * 512];
    unsigned short* dG = &sA[4096 + wv * 512];
    unsigned short* dW = &sA[6144 + wv * 512];
    unsigned short* dQ = &sA[8192 + wv * 512];

    v4f aY[4] = {{0,0,0,0},{0,0,0,0},{0,0,0,0},{0,0,0,0}};
    v4f aT1[4] = {{0,0,0,0},{0,0,0,0},{0,0,0,0},{0,0,0,0}};
    v4f aT2[4] = {{0,0,0,0},{0,0,0,0},{0,0,0,0},{0,0,0,0}};

    for (int kk = 0; kk < kslice; kk += 32) {
        ld16(dF, pF); ld16(dC, pC); ld16(dG, pG); ld16(dW, pW); ld16(dQ, pQ);
        pF += 32; pC += 32; pG += 32; pW += 32; pQ += 32;
        __syncthreads();   // drains LDS-DMA (vmcnt) + joins waves
        v8s f = *(v8s*)&sA[0    + wv * 512 + lane * 8];
        v8s c = *(v8s*)&sA[2048 + wv * 512 + lane * 8];
        v8s g = *(v8s*)&sA[4096 + wv * 512 + lane * 8];
        #pragma unroll
        for (int t = 0; t < 4; ++t) {
            v8s w  = *(v8s*)&sA[6144 + t * 512 + lane * 8];
            v8s w2 = *(v8s*)&sA[8192 + t * 512 + lane * 8];
            aY[t]  = __builtin_amdgcn_mfma_f32_16x16x32_bf16(f, w,  aY[t],  0, 0, 0);
            aT1[t] = __builtin_amdgcn_mfma_f32_16x16x32_bf16(c, w2, aT1[t], 0, 0, 0);
            aT2[t] = __builtin_amdgcn_mfma_f32_16x16x32_bf16(g, w,  aT2[t], 0, 0, 0);
        }
        __syncthreads();
    }

    // C/D layout: col = lane&15, row = (lane>>4)*4 + reg.
    float* pY = partY + (size_t)blockIdx.z * NC;
    float* p1 = partT1 + (size_t)blockIdx.z * NC;
    float* p2 = partT2 + (size_t)blockIdx.z * NC;
    int quad = lane >> 4, colb = lane & 15;
    #pragma unroll
    for (int t = 0; t < 4; ++t) {
        int j = j0 + t * 16 + colb;
        #pragma unroll
        for (int rr = 0; rr < 4; ++rr) {
            int n = n0 + wv * 16 + quad * 4 + rr;
            size_t idx = (size_t)n * Cpad + j;
            pY[idx] = aY[t][rr];
            p1[idx] = aT1[t][rr];
            p2[idx] = aT2[t][rr];
        }
    }
}

// K5: fused epilogue + row loss. One block per row n: sum split-K partials,
// add bias, store y, form isda in registers, logsumexp, rowloss[n].
__global__ __launch_bounds__(256) void epilogue_rowloss(
        const float* __restrict__ partY, const float* __restrict__ partT1,
        const float* __restrict__ partT2, const float* __restrict__ T3p,
        const void* __restrict__ bias, const void* __restrict__ feat,
        const int* __restrict__ labels,
        void* __restrict__ out, size_t off_y,
        float* __restrict__ rowloss,
        int C, int Cpad, int A8, const void* ratio_p, size_t NC) {
    __shared__ float sb[4];
    __shared__ float sM;
    __shared__ float sLabVal;
    int f32m = block_sniff(feat);
    int tid = threadIdx.x;
    int n = blockIdx.x;
    int lab = labels[n];
    float t3 = 0.f;
    for (int i = 0; i < A8; ++i) t3 += T3p[(size_t)lab * A8 + i];
    float ratio = decode_scalar(ratio_p);

    float vals[8];
    int nu = Cpad >> 8;
    float m = -3.4e38f;
    for (int u = 0; u < nu; ++u) {
        int j = u * 256 + tid;
        float v = -3.4e38f;
        if (j < C) {
            size_t idx = (size_t)n * Cpad + j;
            float y = 0.f, t1 = 0.f, t2 = 0.f;
            #pragma unroll
            for (int z = 0; z < KSPLIT; ++z) {
                y  += partY[z * NC + idx];
                t1 += partT1[z * NC + idx];
                t2 += partT2[z * NC + idx];
            }
            y += ldv(bias, j, f32m);
            stv(out, off_y + (size_t)n * C + j, y, f32m);
            v = y + 0.5f * ratio * (t1 - 2.f * t2 + t3);
            if (j == lab) sLabVal = v;
        }
        vals[u] = v;
        m = fmaxf(m, v);
    }
    // block max
    m = wave_max(m);
    int lane = tid & 63, wid = tid >> 6;
    if (lane == 0) sb[wid] = m;
    __syncthreads();
    if (tid == 0) sM = fmaxf(fmaxf(sb[0], sb[1]), fmaxf(sb[2], sb[3]));
    __syncthreads();
    m = sM;
    float s = 0.f;
    for (int u = 0; u < nu; ++u) s += expf(vals[u] - m);   // -inf -> 0
    __syncthreads();
    s = wave_sum(s);
    if (lane == 0) sb[wid] = s;
    __syncthreads();
    if (tid == 0)
        rowloss[n] = m + logf(sb[0] + sb[1] + sb[2] + sb[3]) - sLabVal;
}

// K6: mean of rowloss -> loss scalar (element 0 of out)
__global__ __launch_bounds__(256) void final_loss(
        const float* __restrict__ rowloss, void* __restrict__ out,
        const void* __restrict__ feat, int Nn) {
    __shared__ float sb[4];
    int f32m = block_sniff(feat);
    float s = 0.f;
    for (int i = threadIdx.x; i < Nn; i += 256) s += rowloss[i];
    s = wave_sum(s);
    int lane = threadIdx.x & 63, wid = threadIdx.x >> 6;
    if (lane == 0) sb[wid] = s;
    __syncthreads();
    if (threadIdx.x == 0)
        stv(out, 0, (sb[0] + sb[1] + sb[2] + sb[3]) / (float)Nn, f32m);
}

extern "C" void kernel_launch(void* const* d_in, const int* in_sizes, int n_in,
                              void* d_out, int out_size, void* d_ws, size_t ws_size,
                              hipStream_t stream) {
    const void* feat   = d_in[0];
    const int*  labels = (const int*)d_in[1];
    const void* W      = d_in[2];
    const void* bias   = d_in[3];
    const void* ave    = d_in[4];
    const void* cov    = d_in[5];
    const void* amount = d_in[6];
    const void* ratiop = d_in[7];

    int NA = in_sizes[0];                  // N*A
    int Nn = in_sizes[1];                  // 512
    int C  = in_sizes[3];                  // 1000
    int A  = NA / Nn;                      // 2048
    int CA = in_sizes[2];                  // C*A
    int Cpad = ((C + 255) / 256) * 256;    // 1024
    int A8 = A / 256;                      // 8
    size_t NC = (size_t)Nn * Cpad;

    size_t off_y   = 1;
    size_t off_ave = off_y + (size_t)Nn * C;
    size_t off_cov = off_ave + (size_t)CA;
    size_t off_amt = off_cov + (size_t)CA;

    char* ws = (char*)d_ws;
    int*   w_cnt  = (int*)ws;                          // 1024
    int*   w_off  = w_cnt + 1024;                      // 1024
    int*   w_rows = w_off + 1024;                      // 1024
    float* w_T3p  = (float*)(w_rows + 1024);           // C*A8 (<= 8192)
    float* w_rowls = w_T3p + 8192;                     // 1024
    float* w_partY  = w_rowls + 1024;                  // KSPLIT*NC
    float* w_partT1 = w_partY + KSPLIT * NC;           // KSPLIT*NC
    float* w_partT2 = w_partT1 + KSPLIT * NC;          // KSPLIT*NC
    unsigned short* w_featb = (unsigned short*)(w_partT2 + KSPLIT * NC);  // NA
    unsigned short* w_Wb    = w_featb + NA;            // CA
    unsigned short* w_W2b   = w_Wb + CA;               // CA
    unsigned short* w_Cb    = w_W2b + CA;              // CA
    unsigned short* w_Gb    = w_Cb + CA;               // CA

    count_sort<<<1, 1024, 0, stream>>>(labels, w_cnt, w_off, w_rows, Nn, C);
    prep<<<NA / 2048, 256, 0, stream>>>(feat, w_featb, NA);
    dim3 g2(A8, C);
    finalize_stats<<<g2, 256, 0, stream>>>(w_featb, w_cnt, w_off, w_rows,
                                           ave, cov, amount, W, feat,
                                           d_out, off_ave, off_cov, off_amt,
                                           w_Wb, w_W2b, w_Cb, w_Gb, w_T3p, A, A8);
    dim3 g3(Cpad / 64, Nn / 64, KSPLIT);
    triple_gemm_mfma<<<g3, 256, 0, stream>>>(w_featb, w_Wb, w_W2b, w_Cb, w_Gb,
                                             labels, w_partY, w_partT1, w_partT2,
                                             Cpad, A, NC);
    epilogue_rowloss<<<Nn, 256, 0, stream>>>(w_partY, w_partT1, w_partT2, w_T3p,
                                             bias, feat, labels, d_out, off_y,
                                             w_rowls, C, Cpad, A8, ratiop, NC);
    final_loss<<<1, 256, 0, stream>>>(w_rowls, d_out, feat, Nn);
}